// Round 1
// baseline (121.742 us; speedup 1.0000x reference)
//
#include <hip/hip_runtime.h>

// Problem constants (from reference setup_inputs):
// T=6, B=2, Q=50 -> P=100 queries; N=8 targets; masks 72x72 -> 288x288 (4x bilinear,
// half-pixel centers == align_corners=False); out C[B,Q,N] = 800 floats.

#define T_      6
#define P_      100
#define N_      8
#define HIN     72
#define HOUT    288
#define S_OUT   (HOUT*HOUT)      // 82944
#define NQUAD   (S_OUT/4)        // 20736 float4 quads per mask
#define SPLIT   4
#define QPS     (NQUAD/SPLIT)    // 5184 quads per split block
#define NPAIR   (P_/2)           // 50 query-pairs
#define PART_K  40               // partial floats per (t,pair,split) slot
#define SUMG_OFF (T_*NPAIR*SPLIT*PART_K)   // 48000 floats

__device__ __forceinline__ float fsigmoid(float x) {
    return __builtin_amdgcn_rcpf(1.0f + __expf(-x));
}

#define WRED(x) { x += __shfl_down(x,32); x += __shfl_down(x,16); x += __shfl_down(x,8); \
                  x += __shfl_down(x,4);  x += __shfl_down(x,2);  x += __shfl_down(x,1); }

// ---------------------------------------------------------------------------
// Kernel 1: per (t, query-pair, pixel-split) partial sums.
// Outputs 40 floats per block: dotL/dotS[8] per query, sumL/sumS/iouN/iouD per query.
// ---------------------------------------------------------------------------
__global__ __launch_bounds__(256) void partial_kernel(
    const float* __restrict__ predL, const float* __restrict__ predS,
    const float* __restrict__ tgt, float* __restrict__ ws)
{
    const int blk = blockIdx.x;              // t*200 + pr*4 + sp
    const int t  = blk / (NPAIR*SPLIT);
    const int rem = blk % (NPAIR*SPLIT);
    const int pr = rem / SPLIT;
    const int sp = rem % SPLIT;
    const int p0 = pr*2;

    const float* __restrict__ pL0 = predL + ((size_t)t*P_ + p0) * (HIN*HIN);
    const float* __restrict__ pL1 = pL0 + HIN*HIN;
    const float* __restrict__ pS0 = predS + ((size_t)t*P_ + p0) * (HIN*HIN);
    const float* __restrict__ pS1 = pS0 + HIN*HIN;
    const float4* __restrict__ g4 = (const float4*)(tgt + (size_t)t*N_*S_OUT);

    float dL0[8], dS0[8], dL1[8], dS1[8];
#pragma unroll
    for (int n = 0; n < 8; n++) { dL0[n]=0.f; dS0[n]=0.f; dL1[n]=0.f; dS1[n]=0.f; }
    float sL0=0.f, sS0=0.f, sL1=0.f, sS1=0.f;
    float iN0=0.f, iD0=0.f, iN1=0.f, iD1=0.f;

    const int qend = (sp+1)*QPS;
    for (int qq = sp*QPS + threadIdx.x; qq < qend; qq += 256) {
        const int y  = qq / HIN;            // output row (quads per row == 72)
        const int i  = qq - y*HIN;          // input column block
        const int ry = y & 3;
        const int j  = y >> 2;
        int y0 = (ry < 2) ? (j - 1) : j;
        int y1 = y0 + 1;
        y0 = max(y0, 0); y1 = min(y1, HIN-1);
        const float fy  = (ry==0) ? 0.625f : (ry==1) ? 0.875f : (ry==2) ? 0.125f : 0.375f;
        const float wy0 = 1.0f - fy, wy1 = fy;
        const int im1 = max(i-1, 0), ip1 = min(i+1, HIN-1);
        const int rb0 = y0*HIN, rb1 = y1*HIN;

        float uL0[4], uS0[4], uL1[4], uS1[4];
        auto upsamp = [&](const float* __restrict__ Pp, float u[4]) {
            float am = Pp[rb0+im1], a0 = Pp[rb0+i], ap = Pp[rb0+ip1];
            float bm = Pp[rb1+im1], b0 = Pp[rb1+i], bp = Pp[rb1+ip1];
            float vm = wy0*am + wy1*bm;
            float v0 = wy0*a0 + wy1*b0;
            float vp = wy0*ap + wy1*bp;
            u[0] = 0.375f*vm + 0.625f*v0;
            u[1] = 0.125f*vm + 0.875f*v0;
            u[2] = 0.875f*v0 + 0.125f*vp;
            u[3] = 0.625f*v0 + 0.375f*vp;
        };
        upsamp(pL0, uL0); upsamp(pS0, uS0); upsamp(pL1, uL1); upsamp(pS1, uS1);

        float aL0[4], aS0[4], aL1[4], aS1[4];
#pragma unroll
        for (int r = 0; r < 4; r++) {
            aL0[r] = fsigmoid(uL0[r]); aS0[r] = fsigmoid(uS0[r]);
            aL1[r] = fsigmoid(uL1[r]); aS1[r] = fsigmoid(uS1[r]);
        }
#pragma unroll
        for (int r = 0; r < 4; r++) {
            sL0 += aL0[r]; sS0 += aS0[r]; sL1 += aL1[r]; sS1 += aS1[r];
            float plo0 = (uL0[r] > 0.f) ? aL0[r] : 0.f;
            float pso0 = (uS0[r] > 0.f) ? aS0[r] : 0.f;
            iN0 += plo0 * pso0; iD0 += plo0;
            float plo1 = (uL1[r] > 0.f) ? aL1[r] : 0.f;
            float pso1 = (uS1[r] > 0.f) ? aS1[r] : 0.f;
            iN1 += plo1 * pso1; iD1 += plo1;
        }
#pragma unroll
        for (int n = 0; n < 8; n++) {
            float4 g = g4[n*NQUAD + qq];
            dL0[n] += aL0[0]*g.x + aL0[1]*g.y + aL0[2]*g.z + aL0[3]*g.w;
            dS0[n] += aS0[0]*g.x + aS0[1]*g.y + aS0[2]*g.z + aS0[3]*g.w;
            dL1[n] += aL1[0]*g.x + aL1[1]*g.y + aL1[2]*g.z + aL1[3]*g.w;
            dS1[n] += aS1[0]*g.x + aS1[1]*g.y + aS1[2]*g.z + aS1[3]*g.w;
        }
    }

    // block reduction (4 waves), deterministic single write per slot
#pragma unroll
    for (int n = 0; n < 8; n++) { WRED(dL0[n]); WRED(dS0[n]); WRED(dL1[n]); WRED(dS1[n]); }
    WRED(sL0); WRED(sS0); WRED(iN0); WRED(iD0);
    WRED(sL1); WRED(sS1); WRED(iN1); WRED(iD1);

    __shared__ float red[4][PART_K];
    const int lane = threadIdx.x & 63, wv = threadIdx.x >> 6;
    if (lane == 0) {
        float* r = red[wv];
#pragma unroll
        for (int n = 0; n < 8; n++) { r[n]=dL0[n]; r[8+n]=dS0[n]; r[20+n]=dL1[n]; r[28+n]=dS1[n]; }
        r[16]=sL0; r[17]=sS0; r[18]=iN0; r[19]=iD0;
        r[36]=sL1; r[37]=sS1; r[38]=iN1; r[39]=iD1;
    }
    __syncthreads();
    if (threadIdx.x < PART_K) {
        float v = red[0][threadIdx.x] + red[1][threadIdx.x]
                + red[2][threadIdx.x] + red[3][threadIdx.x];
        ws[(size_t)blk * PART_K + threadIdx.x] = v;
    }
}

// ---------------------------------------------------------------------------
// Kernel 2: per-(t,n) target mask sums (48 values)
// ---------------------------------------------------------------------------
__global__ __launch_bounds__(256) void sumg_kernel(
    const float* __restrict__ tgt, float* __restrict__ ws)
{
    const int blk = blockIdx.x;  // t*8+n
    const float4* __restrict__ g = (const float4*)(tgt + (size_t)blk*S_OUT);
    float s = 0.f;
    for (int idx = threadIdx.x; idx < NQUAD; idx += 256) {
        float4 v = g[idx];
        s += v.x + v.y + v.z + v.w;
    }
    WRED(s);
    __shared__ float r[4];
    if ((threadIdx.x & 63) == 0) r[threadIdx.x >> 6] = s;
    __syncthreads();
    if (threadIdx.x == 0) ws[SUMG_OFF + blk] = r[0]+r[1]+r[2]+r[3];
}

// ---------------------------------------------------------------------------
// Kernel 3: finalize 800 outputs: dice + conditioned IoU + is_referred costs
// ---------------------------------------------------------------------------
__global__ __launch_bounds__(64) void final_kernel(
    const float* __restrict__ pirL, const float* __restrict__ pirS,
    const int* __restrict__ refidx, const float* __restrict__ ws,
    float* __restrict__ out)
{
    const int gid = blockIdx.x*64 + threadIdx.x;
    if (gid >= P_*N_) return;
    const int p = gid >> 3, n = gid & 7;
    const int b = p / 50, q = p % 50;
    const int pr = p >> 1, koff = (p & 1) ? 20 : 0;
    const int rg0 = refidx[0], rg1 = refidx[1] + 4;   // ref_indices[b] + b*(N/B)
    const bool isref = (n == rg0) || (n == rg1);

    float acc = 0.f;
    for (int t = 0; t < T_; t++) {
        const float* base = ws + (size_t)((t*NPAIR + pr)*SPLIT) * PART_K + koff;
        float dL=0.f, dS=0.f, sL=0.f, sS=0.f, iN=0.f, iD=0.f;
#pragma unroll
        for (int sp = 0; sp < SPLIT; sp++) {
            const float* bs = base + sp*PART_K;
            dL += bs[n]; dS += bs[8+n];
            sL += bs[16]; sS += bs[17]; iN += bs[18]; iD += bs[19];
        }
        const float gS = ws[SUMG_OFF + t*8 + n];
        const float diceL = (2.f*dL + 1.f) / (sL + gS + 1.f);
        const float diceS = (2.f*dS + 1.f) / (sS + gS + 1.f);
        const float iou   = (iN + 1.f) / (iD + 1.f);
        const int ib = ((t*2 + b)*50 + q)*2;
        const float l0 = pirL[ib], l1 = pirL[ib+1];
        const float m0 = pirS[ib], m1 = pirS[ib+1];
        // softmax prob of the selected class (0 if referred target, else 1)
        const float pl = isref ? 1.f/(1.f + __expf(l1 - l0)) : 1.f/(1.f + __expf(l0 - l1));
        const float ps = isref ? 1.f/(1.f + __expf(m1 - m0)) : 1.f/(1.f + __expf(m0 - m1));
        acc += diceL + diceS + iou + pl + ps;
    }
    out[gid] = -acc * (1.0f / (float)T_);
}

extern "C" void kernel_launch(void* const* d_in, const int* in_sizes, int n_in,
                              void* d_out, int out_size, void* d_ws, size_t ws_size,
                              hipStream_t stream) {
    const float* predL = (const float*)d_in[0];   // [6,2,50,72,72]
    const float* predS = (const float*)d_in[1];   // [6,2,50,72,72]
    const float* pirL  = (const float*)d_in[2];   // [6,2,50,2]
    const float* pirS  = (const float*)d_in[3];   // [6,2,50,2]
    const float* tgt   = (const float*)d_in[4];   // [6,8,288,288]
    const int*   refix = (const int*)d_in[5];     // [2]
    float* ws  = (float*)d_ws;                    // 48048 floats used (~192 KiB)
    float* out = (float*)d_out;                   // 800 floats

    partial_kernel<<<T_*NPAIR*SPLIT, 256, 0, stream>>>(predL, predS, tgt, ws);
    sumg_kernel<<<T_*N_, 256, 0, stream>>>(tgt, ws);
    final_kernel<<<(P_*N_ + 63)/64, 64, 0, stream>>>(pirL, pirS, refix, ws, out);
}

// Round 2
// 115.573 us; speedup vs baseline: 1.0534x; 1.0534x over previous
//
#include <hip/hip_runtime.h>

// T=6, B=2, Q=50 -> P=100 queries; N=8 targets; 72x72 -> 288x288 bilinear
// (align_corners=False, exact 4x => fixed weights); out C[B,Q,N] = 800 f32.

#define T_      6
#define P_      100
#define N_      8
#define HIN     72
#define HOUT    288
#define S_OUT   (HOUT*HOUT)      // 82944
#define NQUAD   (S_OUT/4)        // 20736 float4 quads per mask
#define SPLIT   8
#define QPS     (NQUAD/SPLIT)    // 2592 quads per split block
#define NPAIR   (P_/2)           // 50 query-pairs
#define PART_K  40               // partial floats per (t,pair,split) slot
#define SUMG_OFF (T_*NPAIR*SPLIT*PART_K)   // 96000 floats

typedef __attribute__((ext_vector_type(2))) float f32x2;

__device__ __forceinline__ float fsigmoid(float x) {
    return __builtin_amdgcn_rcpf(1.0f + __expf(-x));
}

// packed fma, src1 broadcast LOW half to both lanes: d = a * (b.x,b.x) + c
__device__ __forceinline__ f32x2 pkfma_bl(f32x2 a, f32x2 b, f32x2 c) {
    f32x2 d;
    asm("v_pk_fma_f32 %0, %1, %2, %3 op_sel:[0,0,0] op_sel_hi:[1,0,1]"
        : "=v"(d) : "v"(a), "v"(b), "v"(c));
    return d;
}
// packed fma, src1 broadcast HIGH half to both lanes: d = a * (b.y,b.y) + c
__device__ __forceinline__ f32x2 pkfma_bh(f32x2 a, f32x2 b, f32x2 c) {
    f32x2 d;
    asm("v_pk_fma_f32 %0, %1, %2, %3 op_sel:[0,1,0] op_sel_hi:[1,1,1]"
        : "=v"(d) : "v"(a), "v"(b), "v"(c));
    return d;
}

#define WRED(x) { x += __shfl_down(x,32); x += __shfl_down(x,16); x += __shfl_down(x,8); \
                  x += __shfl_down(x,4);  x += __shfl_down(x,2);  x += __shfl_down(x,1); }

// ---------------------------------------------------------------------------
// Kernel 1: per (t, query-pair, pixel-split) partial sums.
// ---------------------------------------------------------------------------
__global__ __launch_bounds__(256) void partial_kernel(
    const float* __restrict__ predL, const float* __restrict__ predS,
    const float* __restrict__ tgt, float* __restrict__ ws)
{
    const int blk = blockIdx.x;              // t*(NPAIR*SPLIT) + pr*SPLIT + sp
    const int t  = blk / (NPAIR*SPLIT);
    const int rem = blk % (NPAIR*SPLIT);
    const int pr = rem / SPLIT;
    const int sp = rem % SPLIT;
    const int p0 = pr*2;

    const float* __restrict__ pL0 = predL + ((size_t)t*P_ + p0) * (HIN*HIN);
    const float* __restrict__ pL1 = pL0 + HIN*HIN;
    const float* __restrict__ pS0 = predS + ((size_t)t*P_ + p0) * (HIN*HIN);
    const float* __restrict__ pS1 = pS0 + HIN*HIN;
    const float4* __restrict__ g4 = (const float4*)(tgt + (size_t)t*N_*S_OUT);

    f32x2 dL[8], dS[8];                      // packed across the query pair
#pragma unroll
    for (int n = 0; n < 8; n++) { dL[n] = (f32x2)(0.f); dS[n] = (f32x2)(0.f); }
    float sL0=0.f, sS0=0.f, sL1=0.f, sS1=0.f;
    float iN0=0.f, iD0=0.f, iN1=0.f, iD1=0.f;

    const int qend = (sp+1)*QPS;
    for (int qq = sp*QPS + threadIdx.x; qq < qend; qq += 256) {
        const int y  = qq / HIN;            // output row (72 quads per row)
        const int i  = qq - y*HIN;          // input column block
        const int ry = y & 3;
        const int j  = y >> 2;
        int y0 = (ry < 2) ? (j - 1) : j;
        int y1 = y0 + 1;
        y0 = max(y0, 0); y1 = min(y1, HIN-1);
        const float fy  = (ry==0) ? 0.625f : (ry==1) ? 0.875f : (ry==2) ? 0.125f : 0.375f;
        const float wy0 = 1.0f - fy, wy1 = fy;
        const int im1 = max(i-1, 0), ip1 = min(i+1, HIN-1);
        const int rb0 = y0*HIN, rb1 = y1*HIN;

        float uL0[4], uS0[4], uL1[4], uS1[4];
        auto upsamp = [&](const float* __restrict__ Pp, float u[4]) {
            float am = Pp[rb0+im1], a0 = Pp[rb0+i], ap = Pp[rb0+ip1];
            float bm = Pp[rb1+im1], b0 = Pp[rb1+i], bp = Pp[rb1+ip1];
            float vm = wy0*am + wy1*bm;
            float v0 = wy0*a0 + wy1*b0;
            float vp = wy0*ap + wy1*bp;
            u[0] = 0.375f*vm + 0.625f*v0;
            u[1] = 0.125f*vm + 0.875f*v0;
            u[2] = 0.875f*v0 + 0.125f*vp;
            u[3] = 0.625f*v0 + 0.375f*vp;
        };
        upsamp(pL0, uL0); upsamp(pS0, uS0); upsamp(pL1, uL1); upsamp(pS1, uS1);

        // sigmoids packed per (query0, query1) pair
        f32x2 aL[4], aS[4];
#pragma unroll
        for (int r = 0; r < 4; r++) {
            aL[r].x = fsigmoid(uL0[r]); aL[r].y = fsigmoid(uL1[r]);
            aS[r].x = fsigmoid(uS0[r]); aS[r].y = fsigmoid(uS1[r]);
        }
#pragma unroll
        for (int r = 0; r < 4; r++) {
            sL0 += aL[r].x; sL1 += aL[r].y; sS0 += aS[r].x; sS1 += aS[r].y;
            float plo0 = (uL0[r] > 0.f) ? aL[r].x : 0.f;
            float pso0 = (uS0[r] > 0.f) ? aS[r].x : 0.f;
            iN0 += plo0 * pso0; iD0 += plo0;
            float plo1 = (uL1[r] > 0.f) ? aL[r].y : 0.f;
            float pso1 = (uS1[r] > 0.f) ? aS[r].y : 0.f;
            iN1 += plo1 * pso1; iD1 += plo1;
        }
#pragma unroll
        for (int n = 0; n < 8; n++) {
            float4 g = g4[n*NQUAD + qq];
            f32x2 gxy; gxy.x = g.x; gxy.y = g.y;
            f32x2 gzw; gzw.x = g.z; gzw.y = g.w;
            dL[n] = pkfma_bl(aL[0], gxy, dL[n]);
            dL[n] = pkfma_bh(aL[1], gxy, dL[n]);
            dL[n] = pkfma_bl(aL[2], gzw, dL[n]);
            dL[n] = pkfma_bh(aL[3], gzw, dL[n]);
            dS[n] = pkfma_bl(aS[0], gxy, dS[n]);
            dS[n] = pkfma_bh(aS[1], gxy, dS[n]);
            dS[n] = pkfma_bl(aS[2], gzw, dS[n]);
            dS[n] = pkfma_bh(aS[3], gzw, dS[n]);
        }
    }

    // unpack packed accumulators, then block reduction
    float dL0[8], dS0[8], dL1[8], dS1[8];
#pragma unroll
    for (int n = 0; n < 8; n++) { dL0[n]=dL[n].x; dL1[n]=dL[n].y; dS0[n]=dS[n].x; dS1[n]=dS[n].y; }
#pragma unroll
    for (int n = 0; n < 8; n++) { WRED(dL0[n]); WRED(dS0[n]); WRED(dL1[n]); WRED(dS1[n]); }
    WRED(sL0); WRED(sS0); WRED(iN0); WRED(iD0);
    WRED(sL1); WRED(sS1); WRED(iN1); WRED(iD1);

    __shared__ float red[4][PART_K];
    const int lane = threadIdx.x & 63, wv = threadIdx.x >> 6;
    if (lane == 0) {
        float* r = red[wv];
#pragma unroll
        for (int n = 0; n < 8; n++) { r[n]=dL0[n]; r[8+n]=dS0[n]; r[20+n]=dL1[n]; r[28+n]=dS1[n]; }
        r[16]=sL0; r[17]=sS0; r[18]=iN0; r[19]=iD0;
        r[36]=sL1; r[37]=sS1; r[38]=iN1; r[39]=iD1;
    }
    __syncthreads();
    if (threadIdx.x < PART_K) {
        float v = red[0][threadIdx.x] + red[1][threadIdx.x]
                + red[2][threadIdx.x] + red[3][threadIdx.x];
        ws[(size_t)blk * PART_K + threadIdx.x] = v;
    }
}

// ---------------------------------------------------------------------------
// Kernel 2: per-(t,n) target mask sums (48 values)
// ---------------------------------------------------------------------------
__global__ __launch_bounds__(256) void sumg_kernel(
    const float* __restrict__ tgt, float* __restrict__ ws)
{
    const int blk = blockIdx.x;  // t*8+n
    const float4* __restrict__ g = (const float4*)(tgt + (size_t)blk*S_OUT);
    float s = 0.f;
    for (int idx = threadIdx.x; idx < NQUAD; idx += 256) {
        float4 v = g[idx];
        s += v.x + v.y + v.z + v.w;
    }
    WRED(s);
    __shared__ float r[4];
    if ((threadIdx.x & 63) == 0) r[threadIdx.x >> 6] = s;
    __syncthreads();
    if (threadIdx.x == 0) ws[SUMG_OFF + blk] = r[0]+r[1]+r[2]+r[3];
}

// ---------------------------------------------------------------------------
// Kernel 3: finalize 800 outputs
// ---------------------------------------------------------------------------
__global__ __launch_bounds__(64) void final_kernel(
    const float* __restrict__ pirL, const float* __restrict__ pirS,
    const int* __restrict__ refidx, const float* __restrict__ ws,
    float* __restrict__ out)
{
    const int gid = blockIdx.x*64 + threadIdx.x;
    if (gid >= P_*N_) return;
    const int p = gid >> 3, n = gid & 7;
    const int b = p / 50, q = p % 50;
    const int pr = p >> 1, koff = (p & 1) ? 20 : 0;
    const int rg0 = refidx[0], rg1 = refidx[1] + 4;   // ref_indices[b] + b*(N/B)
    const bool isref = (n == rg0) || (n == rg1);

    float acc = 0.f;
    for (int t = 0; t < T_; t++) {
        const float* base = ws + (size_t)((t*NPAIR + pr)*SPLIT) * PART_K + koff;
        float dL=0.f, dS=0.f, sL=0.f, sS=0.f, iN=0.f, iD=0.f;
#pragma unroll
        for (int sp = 0; sp < SPLIT; sp++) {
            const float* bs = base + sp*PART_K;
            dL += bs[n]; dS += bs[8+n];
            sL += bs[16]; sS += bs[17]; iN += bs[18]; iD += bs[19];
        }
        const float gS = ws[SUMG_OFF + t*8 + n];
        const float diceL = (2.f*dL + 1.f) / (sL + gS + 1.f);
        const float diceS = (2.f*dS + 1.f) / (sS + gS + 1.f);
        const float iou   = (iN + 1.f) / (iD + 1.f);
        const int ib = ((t*2 + b)*50 + q)*2;
        const float l0 = pirL[ib], l1 = pirL[ib+1];
        const float m0 = pirS[ib], m1 = pirS[ib+1];
        const float pl = isref ? 1.f/(1.f + __expf(l1 - l0)) : 1.f/(1.f + __expf(l0 - l1));
        const float ps = isref ? 1.f/(1.f + __expf(m1 - m0)) : 1.f/(1.f + __expf(m0 - m1));
        acc += diceL + diceS + iou + pl + ps;
    }
    out[gid] = -acc * (1.0f / (float)T_);
}

extern "C" void kernel_launch(void* const* d_in, const int* in_sizes, int n_in,
                              void* d_out, int out_size, void* d_ws, size_t ws_size,
                              hipStream_t stream) {
    const float* predL = (const float*)d_in[0];   // [6,2,50,72,72]
    const float* predS = (const float*)d_in[1];   // [6,2,50,72,72]
    const float* pirL  = (const float*)d_in[2];   // [6,2,50,2]
    const float* pirS  = (const float*)d_in[3];   // [6,2,50,2]
    const float* tgt   = (const float*)d_in[4];   // [6,8,288,288]
    const int*   refix = (const int*)d_in[5];     // [2]
    float* ws  = (float*)d_ws;                    // 96048 floats (~384 KiB)
    float* out = (float*)d_out;                   // 800 floats

    sumg_kernel<<<T_*N_, 256, 0, stream>>>(tgt, ws);
    partial_kernel<<<T_*NPAIR*SPLIT, 256, 0, stream>>>(predL, predS, tgt, ws);
    final_kernel<<<(P_*N_ + 63)/64, 64, 0, stream>>>(pirL, pirS, refix, ws, out);
}